// Round 12
// baseline (112.784 us; speedup 1.0000x reference)
//
#include <hip/hip_runtime.h>
#include <hip/hip_bf16.h>

// GAT MultiHeads, MI355X. N=4096, F_IN=256, H=8, D=16, HD=128.
// All inputs/outputs f32; attention inner loop packed f16 + per-lane bitmasks.
//
// Math identities (vs reference):
//  - logits[h,i,j] = f1[h,j] + f2[h,i]  (rank-1, never materialized)
//  - exp(lrelu(x)) = max(e^x, e^{0.3x})  (exp monotone, lrelu = max(x,0.3x))
//    => q = max(E1[j]*A[i], E3[j]*B[i]); E1=e^f1, E3=e^{0.3f1}, A=e^f2, B=e^{0.3f2}
//  - no max-subtraction: logits bounded (|x| < ~5), softmax ratio invariant
//  - g in {0,1} => mask as bit; applied via v_bfe_i32 sign-mask AND on f16 pairs
//  - denominators = P @ ones via MFMA (idle pipe), lane gets its row sum
//  - fully-masked rows: denom clamp 1e-30 => output row 0 (matches densify)
//
// Pipeline: k_prep (cvt) / k_score (score GEMM + f16 exp tables) /
// k_bits (coalesced ballot compression: 134MB f32 -> 4MB bits, the BW floor) /
// k_attn (j-split x4: no LDS, no barriers, no scalar loads; per-lane bit words)
// / k_reduce (sum partials + output GEMM).
//
// Bit layout: bits[row][cseg][half][e] u32; bit (4*itr+grp) of word (half,e)
//  = mask[row][cseg*512 + half*256 + itr*32 + grp*8 + e]   (itr in [0,8))

#define NN 4096
#define LOG2E 1.44269504088896340736f
#define NS 4          // j-split chunks
#define CHUNK 1024    // NN/NS

typedef short bf16x8 __attribute__((ext_vector_type(8)));
typedef float f32x4  __attribute__((ext_vector_type(4)));
typedef _Float16 h16x8 __attribute__((ext_vector_type(8)));
typedef __fp16  fp16x2 __attribute__((ext_vector_type(2)));

union hu8 { unsigned int u[4]; h16x8 v; };

__device__ __forceinline__ unsigned short f2bf_rn(float f) {
  union { float f; unsigned int i; } v; v.f = f;
  unsigned int r = v.i + 0x7FFFu + ((v.i >> 16) & 1u);  // RTNE
  return (unsigned short)(r >> 16);
}
// two f32 -> packed 2x f16 (RTZ) as u32
__device__ __forceinline__ unsigned int pk2(float lo, float hi) {
  fp16x2 h = __builtin_amdgcn_cvt_pkrtz(lo, hi);
  union { fp16x2 h; unsigned int u; } v; v.h = h; return v.u;
}
// AND-mask for one f16 pair from bit kk of two words: lo16 from wlo, hi16 from whi
__device__ __forceinline__ unsigned int bm16(unsigned wlo, unsigned whi, int kk) {
  int mlo, mhi;
  asm("v_bfe_i32 %0, %1, %2, 1" : "=v"(mlo) : "v"(wlo), "v"(kk));  // 0 or ~0
  asm("v_bfe_i32 %0, %1, %2, 1" : "=v"(mhi) : "v"(whi), "v"(kk));
  return ((unsigned)mlo & 0x0000FFFFu) | ((unsigned)mhi & 0xFFFF0000u);
}

// ---- K0: one-time conversions. grid 512x256 ----
__global__ __launch_bounds__(256) void k_prep(
    const float* __restrict__ X, const float* __restrict__ Ww,
    const float* __restrict__ Wcat, const float* __restrict__ proj,
    const float* __restrict__ Wcb, const float* __restrict__ bias,
    const float* __restrict__ prb,
    unsigned short* __restrict__ Xb, unsigned short* __restrict__ WwT,
    unsigned short* __restrict__ WpT, float* __restrict__ bsum)
{
  const int tid = blockIdx.x * 256 + threadIdx.x;  // 0..131071
  {  // X[4096][256] f32 -> bf16 (RTNE), 8 elements/thread
    const float4 a = *(const float4*)(X + (size_t)tid * 8);
    const float4 b = *(const float4*)(X + (size_t)tid * 8 + 4);
    uint4 o;
    o.x = (unsigned)f2bf_rn(a.x) | ((unsigned)f2bf_rn(a.y) << 16);
    o.y = (unsigned)f2bf_rn(a.z) | ((unsigned)f2bf_rn(a.w) << 16);
    o.z = (unsigned)f2bf_rn(b.x) | ((unsigned)f2bf_rn(b.y) << 16);
    o.w = (unsigned)f2bf_rn(b.z) | ((unsigned)f2bf_rn(b.w) << 16);
    *(uint4*)(Xb + (size_t)tid * 8) = o;
  }
  if (tid < 32768) {  // WwT[c][k] = Ww[k][c], bf16
    int c = tid & 127, k = tid >> 7;
    WwT[c * 256 + k] = f2bf_rn(Ww[k * 128 + c]);
  }
  if (tid < 65536) {  // WpT[c][k]: k<256 -> Wcat[k][c], else proj[k-256][c]
    int c = tid & 127, k = tid >> 7;
    float v = (k < 256) ? Wcat[k * 128 + c] : proj[(k - 256) * 128 + c];
    WpT[c * 512 + k] = f2bf_rn(v);
  }
  if (tid < 128) bsum[tid] = Wcb[tid] + bias[tid] + prb[tid];
}

// ---- K0b: coalesced mask -> bit compression. grid 8192 x 512 ----
// One wave per (graph, row, 512-col segment): 32 B/lane float4 reads,
// 8 ballots, lane 0 writes 64 B of packed words [lo0..lo7, hi0..hi7].
__global__ __launch_bounds__(512) void k_bits(
    const float* __restrict__ Dg, const float* __restrict__ Sg,
    unsigned int* __restrict__ bD, unsigned int* __restrict__ bS)
{
  const int wid = blockIdx.x * 8 + (threadIdx.x >> 6);
  const int lane = threadIdx.x & 63;
  const int g = wid >> 15;            // graph
  const int lid = wid & 32767;
  const int row = lid >> 3, cseg = lid & 7;
  const float* src = (g ? Sg : Dg) + (size_t)row * NN + cseg * 512 + lane * 8;
  const float4 a = *(const float4*)(src);
  const float4 b = *(const float4*)(src + 4);
  unsigned long long m[8];
  m[0] = __ballot(a.x != 0.f); m[1] = __ballot(a.y != 0.f);
  m[2] = __ballot(a.z != 0.f); m[3] = __ballot(a.w != 0.f);
  m[4] = __ballot(b.x != 0.f); m[5] = __ballot(b.y != 0.f);
  m[6] = __ballot(b.z != 0.f); m[7] = __ballot(b.w != 0.f);
  if (lane == 0) {
    unsigned int* dst = (g ? bS : bD) + ((size_t)row * 8 + cseg) * 16;
    uint4 w0, w1, w2, w3;
    w0.x = (unsigned)m[0]; w0.y = (unsigned)m[1];
    w0.z = (unsigned)m[2]; w0.w = (unsigned)m[3];
    w1.x = (unsigned)m[4]; w1.y = (unsigned)m[5];
    w1.z = (unsigned)m[6]; w1.w = (unsigned)m[7];
    w2.x = (unsigned)(m[0] >> 32); w2.y = (unsigned)(m[1] >> 32);
    w2.z = (unsigned)(m[2] >> 32); w2.w = (unsigned)(m[3] >> 32);
    w3.x = (unsigned)(m[4] >> 32); w3.y = (unsigned)(m[5] >> 32);
    w3.z = (unsigned)(m[6] >> 32); w3.w = (unsigned)(m[7] >> 32);
    *(uint4*)(dst)      = w0;
    *(uint4*)(dst + 4)  = w1;
    *(uint4*)(dst + 8)  = w2;
    *(uint4*)(dst + 12) = w3;
  }
}

// ---- K1: score GEMM + f2 + f16 exp tables. grid 256 x 512 ----
__global__ __launch_bounds__(512) void k_score(
    const unsigned short* __restrict__ Xb, const unsigned short* __restrict__ WwT,
    const float* __restrict__ Wb, const float* __restrict__ wu,
    const float* __restrict__ wv,
    unsigned short* __restrict__ scT, float* __restrict__ f2,
    unsigned short* __restrict__ E1p, unsigned short* __restrict__ E3p)
{
  const int n0 = blockIdx.x * 16;
  const int h = threadIdx.x >> 6, lane = threadIdx.x & 63;
  const int mr = lane & 15, grp = lane >> 4;
  const unsigned short* ap  = Xb  + (size_t)(n0 + mr) * 256;
  const unsigned short* bpp = WwT + (size_t)(h * 16 + mr) * 256;
  f32x4 acc = {0.f, 0.f, 0.f, 0.f};
  #pragma unroll
  for (int ks = 0; ks < 8; ++ks) {
    bf16x8 a = *(const bf16x8*)(ap  + ks * 32 + grp * 8);
    bf16x8 b = *(const bf16x8*)(bpp + ks * 32 + grp * 8);
    acc = __builtin_amdgcn_mfma_f32_16x16x32_bf16(a, b, acc, 0, 0, 0);
  }
  const float wb = Wb[h * 16 + mr];
  float sc[4];
  #pragma unroll
  for (int r = 0; r < 4; ++r) sc[r] = acc[r] + wb;  // score[n0+grp*4+r][h*16+mr]

  {  // scT[h*16+mr][n0+grp*4 .. +3] f16
    uint2 st;
    st.x = pk2(sc[0], sc[1]);
    st.y = pk2(sc[2], sc[3]);
    *(uint2*)(scT + (size_t)(h * 16 + mr) * NN + n0 + grp * 4) = st;
  }

  const float uw = wu[h * 16 + mr], vw = wv[h * 16 + mr];
  float t1[4], t2[4];
  #pragma unroll
  for (int r = 0; r < 4; ++r) { t1[r] = sc[r] * uw; t2[r] = sc[r] * vw; }
  #pragma unroll
  for (int m = 1; m < 16; m <<= 1) {
    #pragma unroll
    for (int r = 0; r < 4; ++r) {
      t1[r] += __shfl_xor(t1[r], m, 64);
      t2[r] += __shfl_xor(t2[r], m, 64);
    }
  }
  if (mr == 0) {
    *(float4*)(f2 + h * NN + n0 + grp * 4) = make_float4(t2[0], t2[1], t2[2], t2[3]);
    float e1[4], e3[4];
    #pragma unroll
    for (int r = 0; r < 4; ++r) {
      e1[r] = __builtin_amdgcn_exp2f(t1[r] * LOG2E);
      e3[r] = __builtin_amdgcn_exp2f(0.3f * t1[r] * LOG2E);
    }
    uint2 p1, p3;
    p1.x = pk2(e1[0], e1[1]);
    p1.y = pk2(e1[2], e1[3]);
    p3.x = pk2(e3[0], e3[1]);
    p3.y = pk2(e3[2], e3[3]);
    *(uint2*)(E1p + h * NN + n0 + grp * 4) = p1;
    *(uint2*)(E3p + h * NN + n0 + grp * 4) = p3;
  }
}

// ---- K2: dual-graph masked softmax attention, j-split x NS ----
// grid = NS*256 (bx = chunk*256 + tile), 512 thr (8 waves = 8 heads).
// No LDS, no barriers, no scalar loads: per-lane bit words (uint4 vector
// loads, L2-resident 4 MB) + packed-f16 q; mask via v_bfe_i32 AND-mask.
__global__ __launch_bounds__(512, 6) void k_attn(
    const unsigned int* __restrict__ bD, const unsigned int* __restrict__ bS,
    const unsigned short* __restrict__ scT, const unsigned short* __restrict__ E1p,
    const unsigned short* __restrict__ E3p, const float* __restrict__ f2,
    float* __restrict__ pn, float* __restrict__ pd)
{
  const int bx = blockIdx.x;
  const int c = bx >> 8, t = bx & 255;
  const int i0 = t << 4, j0 = c * CHUNK;
  const int h = threadIdx.x >> 6, lane = threadIdx.x & 63;
  const int mr = lane & 15, grp = lane >> 4;

  const float f2v = f2[h * NN + i0 + mr];
  const _Float16 afh = (_Float16)__builtin_amdgcn_exp2f(f2v * LOG2E);
  const _Float16 bfh = (_Float16)__builtin_amdgcn_exp2f(0.3f * f2v * LOG2E);
  const h16x8 af8 = {afh, afh, afh, afh, afh, afh, afh, afh};
  const h16x8 bf8 = {bfh, bfh, bfh, bfh, bfh, bfh, bfh, bfh};
  const _Float16 one = (_Float16)1.f;
  const h16x8 ones = {one, one, one, one, one, one, one, one};

  const _Float16* e1p_ = (const _Float16*)E1p + h * NN + j0 + grp * 8;
  const _Float16* e3p_ = (const _Float16*)E3p + h * NN + j0 + grp * 8;
  const _Float16* scp_ = (const _Float16*)scT + (size_t)(h * 16 + mr) * NN + j0 + grp * 8;
  // bit words for this lane's row, chunk c covers csegs c*2 .. c*2+1
  const unsigned int* bDr = bD + ((size_t)(i0 + mr) * 8 + c * 2) * 16;
  const unsigned int* bSr = bS + ((size_t)(i0 + mr) * 8 + c * 2) * 16;

  f32x4 accD = {0.f,0.f,0.f,0.f}, accS = {0.f,0.f,0.f,0.f};
  f32x4 dnD  = {0.f,0.f,0.f,0.f}, dnS  = {0.f,0.f,0.f,0.f};

  #pragma unroll
  for (int cs = 0; cs < 2; ++cs) {
    #pragma unroll
    for (int h2 = 0; h2 < 2; ++h2) {
      // words [e0..e7] for this (cseg, half): lo-half bits cover itr 0..7
      const unsigned int* wd = bDr + cs * 16 + h2 * 8;
      const unsigned int* ws_ = bSr + cs * 16 + h2 * 8;
      const uint4 d01 = *(const uint4*)(wd);
      const uint4 d23 = *(const uint4*)(wd + 4);
      const uint4 s01 = *(const uint4*)(ws_);
      const uint4 s23 = *(const uint4*)(ws_ + 4);
      #pragma unroll
      for (int itr = 0; itr < 8; ++itr) {
        const int it = cs * 16 + h2 * 8 + itr;
        const h16x8 e1 = *(const h16x8*)(e1p_ + it * 32);
        const h16x8 e3 = *(const h16x8*)(e3p_ + it * 32);
        const h16x8 sv = *(const h16x8*)(scp_ + it * 32);
        const int kk = itr * 4 + grp;

        hu8 Q, AD, AS;
        Q.v = __builtin_elementwise_max(e1 * af8, e3 * bf8);
        AD.u[0] = Q.u[0] & bm16(d01.x, d01.y, kk);
        AD.u[1] = Q.u[1] & bm16(d01.z, d01.w, kk);
        AD.u[2] = Q.u[2] & bm16(d23.x, d23.y, kk);
        AD.u[3] = Q.u[3] & bm16(d23.z, d23.w, kk);
        AS.u[0] = Q.u[0] & bm16(s01.x, s01.y, kk);
        AS.u[1] = Q.u[1] & bm16(s01.z, s01.w, kk);
        AS.u[2] = Q.u[2] & bm16(s23.x, s23.y, kk);
        AS.u[3] = Q.u[3] & bm16(s23.z, s23.w, kk);

        accD = __builtin_amdgcn_mfma_f32_16x16x32_f16(AD.v, sv, accD, 0, 0, 0);
        accS = __builtin_amdgcn_mfma_f32_16x16x32_f16(AS.v, sv, accS, 0, 0, 0);
        dnD  = __builtin_amdgcn_mfma_f32_16x16x32_f16(AD.v, ones, dnD, 0, 0, 0);
        dnS  = __builtin_amdgcn_mfma_f32_16x16x32_f16(AS.v, ones, dnS, 0, 0, 0);
      }
    }
  }

  // partials: pn[((c*256+t)*8+h)*2+g][row][col], pd[((c*256+t)*8+h)*2+g][row]
  float* pnb = pn + ((((size_t)c * 256 + t) * 8 + h) * 2) * 256;
  #pragma unroll
  for (int r = 0; r < 4; ++r) {
    const int row = grp * 4 + r;
    pnb[row * 16 + mr]       = accD[r];
    pnb[256 + row * 16 + mr] = accS[r];
  }
  if (mr == 0) {
    float* pdb = pd + ((((size_t)c * 256 + t) * 8 + h) * 2) * 16;
    #pragma unroll
    for (int r = 0; r < 4; ++r) {
      pdb[grp * 4 + r]      = dnD[r];
      pdb[16 + grp * 4 + r] = dnS[r];
    }
  }
}

// ---- K3: reduce partials, normalize, output GEMM. grid 256 x 512 ----
__global__ __launch_bounds__(512) void k_reduce(
    const float* __restrict__ pn, const float* __restrict__ pd,
    const unsigned short* __restrict__ Xb, const unsigned short* __restrict__ WpT,
    const float* __restrict__ bsum, float* __restrict__ out)
{
  __shared__ unsigned short catT[16][520];  // [row][ S(128) | D(128) | X(256) ]
  const int t = blockIdx.x, i0 = t * 16;
  const int tid = threadIdx.x;
  {  // stage X rows -> catT cols 256..511
    const int r = tid >> 5, x0 = (tid & 31) * 8;
    *(bf16x8*)(&catT[r][256 + x0]) = *(const bf16x8*)(Xb + (size_t)(i0 + r) * 256 + x0);
  }
  const int h = tid >> 6, lane = tid & 63;
  const int mr = lane & 15, grp = lane >> 4;

  #pragma unroll
  for (int r = 0; r < 4; ++r) {
    const int row = grp * 4 + r;
    float vD = 0.f, vS = 0.f, dD = 0.f, dS = 0.f;
    #pragma unroll
    for (int c = 0; c < NS; ++c) {
      const size_t nb = ((((size_t)c * 256 + t) * 8 + h) * 2) * 256;
      const size_t db = ((((size_t)c * 256 + t) * 8 + h) * 2) * 16;
      vD += pn[nb + row * 16 + mr];
      vS += pn[nb + 256 + row * 16 + mr];
      dD += pd[db + row];
      dS += pd[db + 16 + row];
    }
    const float oS = vS * __builtin_amdgcn_rcpf(fmaxf(dS, 1e-30f));
    const float oD = vD * __builtin_amdgcn_rcpf(fmaxf(dD, 1e-30f));
    catT[row][h * 16 + mr]       = f2bf_rn(oS);
    catT[row][128 + h * 16 + mr] = f2bf_rn(oD);
  }
  __syncthreads();

  // phase B: out[16][128] = catT[16][512] @ W'[512][128] + bsum
  f32x4 o = {0.f, 0.f, 0.f, 0.f};
  const unsigned short* wp = WpT + (size_t)(h * 16 + mr) * 512;
  #pragma unroll
  for (int ks = 0; ks < 16; ++ks) {
    bf16x8 a = *(const bf16x8*)(&catT[mr][ks * 32 + grp * 8]);
    bf16x8 b = *(const bf16x8*)(wp + ks * 32 + grp * 8);
    o = __builtin_amdgcn_mfma_f32_16x16x32_bf16(a, b, o, 0, 0, 0);
  }
  const float bs = bsum[h * 16 + mr];
  #pragma unroll
  for (int r = 0; r < 4; ++r)
    out[(size_t)(i0 + grp * 4 + r) * 128 + h * 16 + mr] = o[r] + bs;
}

extern "C" void kernel_launch(void* const* d_in, const int* in_sizes, int n_in,
                              void* d_out, int out_size, void* d_ws, size_t ws_size,
                              hipStream_t stream) {
  const float* X    = (const float*)d_in[0];
  const float* Dg   = (const float*)d_in[1];
  const float* Sg   = (const float*)d_in[2];
  const float* Ww   = (const float*)d_in[3];
  const float* Wb   = (const float*)d_in[4];
  const float* wu   = (const float*)d_in[5];
  const float* wv   = (const float*)d_in[6];
  const float* Wcat = (const float*)d_in[7];
  const float* Wcb  = (const float*)d_in[8];
  const float* bias = (const float*)d_in[9];
  const float* proj = (const float*)d_in[10];
  const float* prb  = (const float*)d_in[11];
  float* out = (float*)d_out;

  char* ws = (char*)d_ws;
  unsigned short* Xb   = (unsigned short*)(ws);              // 2 MB
  unsigned short* scT  = (unsigned short*)(ws + 0x200000);   // 1 MB (f16)
  float*          f2   = (float*)(ws + 0x300000);            // 128 KB
  unsigned short* E1p  = (unsigned short*)(ws + 0x320000);   // 64 KB (f16)
  unsigned short* E3p  = (unsigned short*)(ws + 0x330000);   // 64 KB (f16)
  unsigned short* WwT  = (unsigned short*)(ws + 0x340000);   // 64 KB
  unsigned short* WpT  = (unsigned short*)(ws + 0x350000);   // 128 KB
  float*          bsum = (float*)(ws + 0x370000);            // 512 B
  unsigned int*   bD   = (unsigned int*)(ws + 0x380000);     // 2 MB
  unsigned int*   bS   = (unsigned int*)(ws + 0x580000);     // 2 MB
  float*          pn   = (float*)(ws + 0x780000);            // 16 MB
  float*          pd   = (float*)(ws + 0x1780000);           // 1 MB

  k_prep<<<dim3(512), dim3(256), 0, stream>>>(X, Ww, Wcat, proj, Wcb, bias, prb,
                                              Xb, WwT, WpT, bsum);
  k_bits<<<dim3(8192), dim3(512), 0, stream>>>(Dg, Sg, bD, bS);
  k_score<<<dim3(256), dim3(512), 0, stream>>>(Xb, WwT, Wb, wu, wv, scT, f2, E1p, E3p);
  k_attn<<<dim3(NS * 256), dim3(512), 0, stream>>>(bD, bS, scT, E1p, E3p, f2, pn, pd);
  k_reduce<<<dim3(256), dim3(512), 0, stream>>>(pn, pd, Xb, WpT, bsum, out);
}

// Round 13
// 112.725 us; speedup vs baseline: 1.0005x; 1.0005x over previous
//
#include <hip/hip_runtime.h>
#include <hip/hip_bf16.h>

// GAT MultiHeads, MI355X. N=4096, F_IN=256, H=8, D=16, HD=128.
// All inputs/outputs f32; attention inner loop packed f16 + per-lane bitmasks.
//
// Math identities (vs reference):
//  - logits[h,i,j] = f1[h,j] + f2[h,i]  (rank-1, never materialized)
//  - exp(lrelu(x)) = max(e^x, e^{0.3x})  (exp monotone, lrelu = max(x,0.3x))
//    => q = max(E1[j]*A[i], E3[j]*B[i]); E1=e^f1, E3=e^{0.3f1}, A=e^f2, B=e^{0.3f2}
//  - no max-subtraction: logits bounded (|x| < ~5), softmax ratio invariant
//  - g in {0,1} => mask as bit; applied via v_bfe_i32 sign-mask AND on f16 pairs
//  - denominators = P @ ones via MFMA (idle pipe), lane gets its row sum
//  - fully-masked rows: denom clamp 1e-30 => output row 0 (matches densify)
//
// Pipeline: k_prep (cvt) / k_score (score GEMM + f16 exp tables) /
// k_bits (coalesced ballot compression: 134MB f32 -> 4MB bits, the BW floor) /
// k_attn (j-split x4: no LDS, no barriers, no scalar loads; per-lane bit words)
// / k_reduce (sum partials + output GEMM).
//
// Bit layout: bits[row][cseg][half][e] u32; bit (4*itr+grp) of word (half,e)
//  = mask[row][cseg*512 + half*256 + itr*32 + grp*8 + e]   (itr in [0,8))

#define NN 4096
#define LOG2E 1.44269504088896340736f
#define NS 4          // j-split chunks
#define CHUNK 1024    // NN/NS

typedef short bf16x8 __attribute__((ext_vector_type(8)));
typedef float f32x4  __attribute__((ext_vector_type(4)));
typedef _Float16 h16x8 __attribute__((ext_vector_type(8)));
typedef __fp16  fp16x2 __attribute__((ext_vector_type(2)));

union hu8 { unsigned int u[4]; h16x8 v; };

__device__ __forceinline__ unsigned short f2bf_rn(float f) {
  union { float f; unsigned int i; } v; v.f = f;
  unsigned int r = v.i + 0x7FFFu + ((v.i >> 16) & 1u);  // RTNE
  return (unsigned short)(r >> 16);
}
// two f32 -> packed 2x f16 (RTZ) as u32
__device__ __forceinline__ unsigned int pk2(float lo, float hi) {
  fp16x2 h = __builtin_amdgcn_cvt_pkrtz(lo, hi);
  union { fp16x2 h; unsigned int u; } v; v.h = h; return v.u;
}
// AND-mask for one f16 pair from bit kk of two words: lo16 from wlo, hi16 from whi
__device__ __forceinline__ unsigned int bm16(unsigned wlo, unsigned whi, int kk) {
  int mlo, mhi;
  asm("v_bfe_i32 %0, %1, %2, 1" : "=v"(mlo) : "v"(wlo), "v"(kk));  // 0 or ~0
  asm("v_bfe_i32 %0, %1, %2, 1" : "=v"(mhi) : "v"(whi), "v"(kk));
  return ((unsigned)mlo & 0x0000FFFFu) | ((unsigned)mhi & 0xFFFF0000u);
}

// ---- K0: one-time conversions. grid 512x256 ----
__global__ __launch_bounds__(256) void k_prep(
    const float* __restrict__ X, const float* __restrict__ Ww,
    const float* __restrict__ Wcat, const float* __restrict__ proj,
    const float* __restrict__ Wcb, const float* __restrict__ bias,
    const float* __restrict__ prb,
    unsigned short* __restrict__ Xb, unsigned short* __restrict__ WwT,
    unsigned short* __restrict__ WpT, float* __restrict__ bsum)
{
  const int tid = blockIdx.x * 256 + threadIdx.x;  // 0..131071
  {  // X[4096][256] f32 -> bf16 (RTNE), 8 elements/thread
    const float4 a = *(const float4*)(X + (size_t)tid * 8);
    const float4 b = *(const float4*)(X + (size_t)tid * 8 + 4);
    uint4 o;
    o.x = (unsigned)f2bf_rn(a.x) | ((unsigned)f2bf_rn(a.y) << 16);
    o.y = (unsigned)f2bf_rn(a.z) | ((unsigned)f2bf_rn(a.w) << 16);
    o.z = (unsigned)f2bf_rn(b.x) | ((unsigned)f2bf_rn(b.y) << 16);
    o.w = (unsigned)f2bf_rn(b.z) | ((unsigned)f2bf_rn(b.w) << 16);
    *(uint4*)(Xb + (size_t)tid * 8) = o;
  }
  if (tid < 32768) {  // WwT[c][k] = Ww[k][c], bf16
    int c = tid & 127, k = tid >> 7;
    WwT[c * 256 + k] = f2bf_rn(Ww[k * 128 + c]);
  }
  if (tid < 65536) {  // WpT[c][k]: k<256 -> Wcat[k][c], else proj[k-256][c]
    int c = tid & 127, k = tid >> 7;
    float v = (k < 256) ? Wcat[k * 128 + c] : proj[(k - 256) * 128 + c];
    WpT[c * 512 + k] = f2bf_rn(v);
  }
  if (tid < 128) bsum[tid] = Wcb[tid] + bias[tid] + prb[tid];
}

// ---- K0b: coalesced mask -> bit compression. grid 8192 x 512 ----
// One wave per (graph, row, 512-col segment): 32 B/lane float4 reads,
// 8 ballots, lane 0 writes 64 B of packed words [lo0..lo7, hi0..hi7].
__global__ __launch_bounds__(512) void k_bits(
    const float* __restrict__ Dg, const float* __restrict__ Sg,
    unsigned int* __restrict__ bD, unsigned int* __restrict__ bS)
{
  const int wid = blockIdx.x * 8 + (threadIdx.x >> 6);
  const int lane = threadIdx.x & 63;
  const int g = wid >> 15;            // graph
  const int lid = wid & 32767;
  const int row = lid >> 3, cseg = lid & 7;
  const float* src = (g ? Sg : Dg) + (size_t)row * NN + cseg * 512 + lane * 8;
  const float4 a = *(const float4*)(src);
  const float4 b = *(const float4*)(src + 4);
  unsigned long long m[8];
  m[0] = __ballot(a.x != 0.f); m[1] = __ballot(a.y != 0.f);
  m[2] = __ballot(a.z != 0.f); m[3] = __ballot(a.w != 0.f);
  m[4] = __ballot(b.x != 0.f); m[5] = __ballot(b.y != 0.f);
  m[6] = __ballot(b.z != 0.f); m[7] = __ballot(b.w != 0.f);
  if (lane == 0) {
    unsigned int* dst = (g ? bS : bD) + ((size_t)row * 8 + cseg) * 16;
    uint4 w0, w1, w2, w3;
    w0.x = (unsigned)m[0]; w0.y = (unsigned)m[1];
    w0.z = (unsigned)m[2]; w0.w = (unsigned)m[3];
    w1.x = (unsigned)m[4]; w1.y = (unsigned)m[5];
    w1.z = (unsigned)m[6]; w1.w = (unsigned)m[7];
    w2.x = (unsigned)(m[0] >> 32); w2.y = (unsigned)(m[1] >> 32);
    w2.z = (unsigned)(m[2] >> 32); w2.w = (unsigned)(m[3] >> 32);
    w3.x = (unsigned)(m[4] >> 32); w3.y = (unsigned)(m[5] >> 32);
    w3.z = (unsigned)(m[6] >> 32); w3.w = (unsigned)(m[7] >> 32);
    *(uint4*)(dst)      = w0;
    *(uint4*)(dst + 4)  = w1;
    *(uint4*)(dst + 8)  = w2;
    *(uint4*)(dst + 12) = w3;
  }
}

// ---- K1: score GEMM + f2 + f16 exp tables. grid 256 x 512 ----
__global__ __launch_bounds__(512) void k_score(
    const unsigned short* __restrict__ Xb, const unsigned short* __restrict__ WwT,
    const float* __restrict__ Wb, const float* __restrict__ wu,
    const float* __restrict__ wv,
    unsigned short* __restrict__ scT, float* __restrict__ f2,
    unsigned short* __restrict__ E1p, unsigned short* __restrict__ E3p)
{
  const int n0 = blockIdx.x * 16;
  const int h = threadIdx.x >> 6, lane = threadIdx.x & 63;
  const int mr = lane & 15, grp = lane >> 4;
  const unsigned short* ap  = Xb  + (size_t)(n0 + mr) * 256;
  const unsigned short* bpp = WwT + (size_t)(h * 16 + mr) * 256;
  f32x4 acc = {0.f, 0.f, 0.f, 0.f};
  #pragma unroll
  for (int ks = 0; ks < 8; ++ks) {
    bf16x8 a = *(const bf16x8*)(ap  + ks * 32 + grp * 8);
    bf16x8 b = *(const bf16x8*)(bpp + ks * 32 + grp * 8);
    acc = __builtin_amdgcn_mfma_f32_16x16x32_bf16(a, b, acc, 0, 0, 0);
  }
  const float wb = Wb[h * 16 + mr];
  float sc[4];
  #pragma unroll
  for (int r = 0; r < 4; ++r) sc[r] = acc[r] + wb;  // score[n0+grp*4+r][h*16+mr]

  {  // scT[h*16+mr][n0+grp*4 .. +3] f16
    uint2 st;
    st.x = pk2(sc[0], sc[1]);
    st.y = pk2(sc[2], sc[3]);
    *(uint2*)(scT + (size_t)(h * 16 + mr) * NN + n0 + grp * 4) = st;
  }

  const float uw = wu[h * 16 + mr], vw = wv[h * 16 + mr];
  float t1[4], t2[4];
  #pragma unroll
  for (int r = 0; r < 4; ++r) { t1[r] = sc[r] * uw; t2[r] = sc[r] * vw; }
  #pragma unroll
  for (int m = 1; m < 16; m <<= 1) {
    #pragma unroll
    for (int r = 0; r < 4; ++r) {
      t1[r] += __shfl_xor(t1[r], m, 64);
      t2[r] += __shfl_xor(t2[r], m, 64);
    }
  }
  if (mr == 0) {
    *(float4*)(f2 + h * NN + n0 + grp * 4) = make_float4(t2[0], t2[1], t2[2], t2[3]);
    float e1[4], e3[4];
    #pragma unroll
    for (int r = 0; r < 4; ++r) {
      e1[r] = __builtin_amdgcn_exp2f(t1[r] * LOG2E);
      e3[r] = __builtin_amdgcn_exp2f(0.3f * t1[r] * LOG2E);
    }
    uint2 p1, p3;
    p1.x = pk2(e1[0], e1[1]);
    p1.y = pk2(e1[2], e1[3]);
    p3.x = pk2(e3[0], e3[1]);
    p3.y = pk2(e3[2], e3[3]);
    *(uint2*)(E1p + h * NN + n0 + grp * 4) = p1;
    *(uint2*)(E3p + h * NN + n0 + grp * 4) = p3;
  }
}

// ---- K2: dual-graph masked softmax attention, j-split x NS ----
// grid = NS*256 (bx = chunk*256 + tile), 512 thr (8 waves = 8 heads).
// No LDS, no barriers, no scalar loads: per-lane bit words (uint4 vector
// loads, L2-resident 4 MB) + packed-f16 q; mask via v_bfe_i32 AND-mask.
__global__ __launch_bounds__(512, 6) void k_attn(
    const unsigned int* __restrict__ bD, const unsigned int* __restrict__ bS,
    const unsigned short* __restrict__ scT, const unsigned short* __restrict__ E1p,
    const unsigned short* __restrict__ E3p, const float* __restrict__ f2,
    float* __restrict__ pn, float* __restrict__ pd)
{
  const int bx = blockIdx.x;
  const int c = bx >> 8, t = bx & 255;
  const int i0 = t << 4, j0 = c * CHUNK;
  const int h = threadIdx.x >> 6, lane = threadIdx.x & 63;
  const int mr = lane & 15, grp = lane >> 4;

  const float f2v = f2[h * NN + i0 + mr];
  const _Float16 afh = (_Float16)__builtin_amdgcn_exp2f(f2v * LOG2E);
  const _Float16 bfh = (_Float16)__builtin_amdgcn_exp2f(0.3f * f2v * LOG2E);
  const h16x8 af8 = {afh, afh, afh, afh, afh, afh, afh, afh};
  const h16x8 bf8 = {bfh, bfh, bfh, bfh, bfh, bfh, bfh, bfh};
  const _Float16 one = (_Float16)1.f;
  const h16x8 ones = {one, one, one, one, one, one, one, one};

  const _Float16* e1p_ = (const _Float16*)E1p + h * NN + j0 + grp * 8;
  const _Float16* e3p_ = (const _Float16*)E3p + h * NN + j0 + grp * 8;
  const _Float16* scp_ = (const _Float16*)scT + (size_t)(h * 16 + mr) * NN + j0 + grp * 8;
  // bit words for this lane's row, chunk c covers csegs c*2 .. c*2+1
  const unsigned int* bDr = bD + ((size_t)(i0 + mr) * 8 + c * 2) * 16;
  const unsigned int* bSr = bS + ((size_t)(i0 + mr) * 8 + c * 2) * 16;

  f32x4 accD = {0.f,0.f,0.f,0.f}, accS = {0.f,0.f,0.f,0.f};
  f32x4 dnD  = {0.f,0.f,0.f,0.f}, dnS  = {0.f,0.f,0.f,0.f};

  #pragma unroll
  for (int cs = 0; cs < 2; ++cs) {
    #pragma unroll
    for (int h2 = 0; h2 < 2; ++h2) {
      // words [e0..e7] for this (cseg, half): lo-half bits cover itr 0..7
      const unsigned int* wd = bDr + cs * 16 + h2 * 8;
      const unsigned int* ws_ = bSr + cs * 16 + h2 * 8;
      const uint4 d01 = *(const uint4*)(wd);
      const uint4 d23 = *(const uint4*)(wd + 4);
      const uint4 s01 = *(const uint4*)(ws_);
      const uint4 s23 = *(const uint4*)(ws_ + 4);
      #pragma unroll
      for (int itr = 0; itr < 8; ++itr) {
        const int it = cs * 16 + h2 * 8 + itr;
        const h16x8 e1 = *(const h16x8*)(e1p_ + it * 32);
        const h16x8 e3 = *(const h16x8*)(e3p_ + it * 32);
        const h16x8 sv = *(const h16x8*)(scp_ + it * 32);
        const int kk = itr * 4 + grp;

        hu8 Q, AD, AS;
        Q.v = __builtin_elementwise_max(e1 * af8, e3 * bf8);
        AD.u[0] = Q.u[0] & bm16(d01.x, d01.y, kk);
        AD.u[1] = Q.u[1] & bm16(d01.z, d01.w, kk);
        AD.u[2] = Q.u[2] & bm16(d23.x, d23.y, kk);
        AD.u[3] = Q.u[3] & bm16(d23.z, d23.w, kk);
        AS.u[0] = Q.u[0] & bm16(s01.x, s01.y, kk);
        AS.u[1] = Q.u[1] & bm16(s01.z, s01.w, kk);
        AS.u[2] = Q.u[2] & bm16(s23.x, s23.y, kk);
        AS.u[3] = Q.u[3] & bm16(s23.z, s23.w, kk);

        accD = __builtin_amdgcn_mfma_f32_16x16x32_f16(AD.v, sv, accD, 0, 0, 0);
        accS = __builtin_amdgcn_mfma_f32_16x16x32_f16(AS.v, sv, accS, 0, 0, 0);
        dnD  = __builtin_amdgcn_mfma_f32_16x16x32_f16(AD.v, ones, dnD, 0, 0, 0);
        dnS  = __builtin_amdgcn_mfma_f32_16x16x32_f16(AS.v, ones, dnS, 0, 0, 0);
      }
    }
  }

  // partials: pn[((c*256+t)*8+h)*2+g][row][col], pd[((c*256+t)*8+h)*2+g][row]
  float* pnb = pn + ((((size_t)c * 256 + t) * 8 + h) * 2) * 256;
  #pragma unroll
  for (int r = 0; r < 4; ++r) {
    const int row = grp * 4 + r;
    pnb[row * 16 + mr]       = accD[r];
    pnb[256 + row * 16 + mr] = accS[r];
  }
  if (mr == 0) {
    float* pdb = pd + ((((size_t)c * 256 + t) * 8 + h) * 2) * 16;
    #pragma unroll
    for (int r = 0; r < 4; ++r) {
      pdb[grp * 4 + r]      = dnD[r];
      pdb[16 + grp * 4 + r] = dnS[r];
    }
  }
}

// ---- K3: reduce partials, normalize, output GEMM. grid 256 x 512 ----
__global__ __launch_bounds__(512) void k_reduce(
    const float* __restrict__ pn, const float* __restrict__ pd,
    const unsigned short* __restrict__ Xb, const unsigned short* __restrict__ WpT,
    const float* __restrict__ bsum, float* __restrict__ out)
{
  __shared__ unsigned short catT[16][520];  // [row][ S(128) | D(128) | X(256) ]
  const int t = blockIdx.x, i0 = t * 16;
  const int tid = threadIdx.x;
  {  // stage X rows -> catT cols 256..511
    const int r = tid >> 5, x0 = (tid & 31) * 8;
    *(bf16x8*)(&catT[r][256 + x0]) = *(const bf16x8*)(Xb + (size_t)(i0 + r) * 256 + x0);
  }
  const int h = tid >> 6, lane = tid & 63;
  const int mr = lane & 15, grp = lane >> 4;

  #pragma unroll
  for (int r = 0; r < 4; ++r) {
    const int row = grp * 4 + r;
    float vD = 0.f, vS = 0.f, dD = 0.f, dS = 0.f;
    #pragma unroll
    for (int c = 0; c < NS; ++c) {
      const size_t nb = ((((size_t)c * 256 + t) * 8 + h) * 2) * 256;
      const size_t db = ((((size_t)c * 256 + t) * 8 + h) * 2) * 16;
      vD += pn[nb + row * 16 + mr];
      vS += pn[nb + 256 + row * 16 + mr];
      dD += pd[db + row];
      dS += pd[db + 16 + row];
    }
    const float oS = vS * __builtin_amdgcn_rcpf(fmaxf(dS, 1e-30f));
    const float oD = vD * __builtin_amdgcn_rcpf(fmaxf(dD, 1e-30f));
    catT[row][h * 16 + mr]       = f2bf_rn(oS);
    catT[row][128 + h * 16 + mr] = f2bf_rn(oD);
  }
  __syncthreads();

  // phase B: out[16][128] = catT[16][512] @ W'[512][128] + bsum
  f32x4 o = {0.f, 0.f, 0.f, 0.f};
  const unsigned short* wp = WpT + (size_t)(h * 16 + mr) * 512;
  #pragma unroll
  for (int ks = 0; ks < 16; ++ks) {
    bf16x8 a = *(const bf16x8*)(&catT[mr][ks * 32 + grp * 8]);
    bf16x8 b = *(const bf16x8*)(wp + ks * 32 + grp * 8);
    o = __builtin_amdgcn_mfma_f32_16x16x32_bf16(a, b, o, 0, 0, 0);
  }
  const float bs = bsum[h * 16 + mr];
  #pragma unroll
  for (int r = 0; r < 4; ++r)
    out[(size_t)(i0 + grp * 4 + r) * 128 + h * 16 + mr] = o[r] + bs;
}

extern "C" void kernel_launch(void* const* d_in, const int* in_sizes, int n_in,
                              void* d_out, int out_size, void* d_ws, size_t ws_size,
                              hipStream_t stream) {
  const float* X    = (const float*)d_in[0];
  const float* Dg   = (const float*)d_in[1];
  const float* Sg   = (const float*)d_in[2];
  const float* Ww   = (const float*)d_in[3];
  const float* Wb   = (const float*)d_in[4];
  const float* wu   = (const float*)d_in[5];
  const float* wv   = (const float*)d_in[6];
  const float* Wcat = (const float*)d_in[7];
  const float* Wcb  = (const float*)d_in[8];
  const float* bias = (const float*)d_in[9];
  const float* proj = (const float*)d_in[10];
  const float* prb  = (const float*)d_in[11];
  float* out = (float*)d_out;

  char* ws = (char*)d_ws;
  unsigned short* Xb   = (unsigned short*)(ws);              // 2 MB
  unsigned short* scT  = (unsigned short*)(ws + 0x200000);   // 1 MB (f16)
  float*          f2   = (float*)(ws + 0x300000);            // 128 KB
  unsigned short* E1p  = (unsigned short*)(ws + 0x320000);   // 64 KB (f16)
  unsigned short* E3p  = (unsigned short*)(ws + 0x330000);   // 64 KB (f16)
  unsigned short* WwT  = (unsigned short*)(ws + 0x340000);   // 64 KB
  unsigned short* WpT  = (unsigned short*)(ws + 0x350000);   // 128 KB
  float*          bsum = (float*)(ws + 0x370000);            // 512 B
  unsigned int*   bD   = (unsigned int*)(ws + 0x380000);     // 2 MB
  unsigned int*   bS   = (unsigned int*)(ws + 0x580000);     // 2 MB
  float*          pn   = (float*)(ws + 0x780000);            // 16 MB
  float*          pd   = (float*)(ws + 0x1780000);           // 1 MB

  k_prep<<<dim3(512), dim3(256), 0, stream>>>(X, Ww, Wcat, proj, Wcb, bias, prb,
                                              Xb, WwT, WpT, bsum);
  k_bits<<<dim3(8192), dim3(512), 0, stream>>>(Dg, Sg, bD, bS);
  k_score<<<dim3(256), dim3(512), 0, stream>>>(Xb, WwT, Wb, wu, wv, scT, f2, E1p, E3p);
  k_attn<<<dim3(NS * 256), dim3(512), 0, stream>>>(bD, bS, scT, E1p, E3p, f2, pn, pd);
  k_reduce<<<dim3(256), dim3(512), 0, stream>>>(pn, pd, Xb, WpT, bsum, out);
}

// Round 14
// 112.677 us; speedup vs baseline: 1.0010x; 1.0004x over previous
//
#include <hip/hip_runtime.h>
#include <hip/hip_bf16.h>

// GAT MultiHeads, MI355X. N=4096, F_IN=256, H=8, D=16, HD=128.
// All inputs/outputs f32; attention inner loop packed f16 + per-lane bitmasks.
//
// Math identities (vs reference):
//  - logits[h,i,j] = f1[h,j] + f2[h,i]  (rank-1, never materialized)
//  - exp(lrelu(x)) = max(e^x, e^{0.3x})  (exp monotone, lrelu = max(x,0.3x))
//    => q = max(E1[j]*A[i], E3[j]*B[i]); E1=e^f1, E3=e^{0.3f1}, A=e^f2, B=e^{0.3f2}
//  - no max-subtraction: logits bounded (|x| < ~5), softmax ratio invariant
//  - g in {0,1} => mask as bit; applied via v_bfe_i32 sign-mask AND on f16 pairs
//  - denominators = P @ ones via MFMA (idle pipe), lane gets its row sum
//  - fully-masked rows: denom clamp 1e-30 => output row 0 (matches densify)
//
// Pipeline: k_prep (cvt) / k_score (score GEMM + f16 exp tables) /
// k_bits (coalesced ballot compression: 134MB f32 -> 4MB bits, the BW floor) /
// k_attn (j-split x4: no LDS, no barriers, no scalar loads; per-lane bit words)
// / k_reduce (sum partials + output GEMM).
//
// Bit layout: bits[row][cseg][half][e] u32; bit (4*itr+grp) of word (half,e)
//  = mask[row][cseg*512 + half*256 + itr*32 + grp*8 + e]   (itr in [0,8))

#define NN 4096
#define LOG2E 1.44269504088896340736f
#define NS 4          // j-split chunks
#define CHUNK 1024    // NN/NS

typedef short bf16x8 __attribute__((ext_vector_type(8)));
typedef float f32x4  __attribute__((ext_vector_type(4)));
typedef _Float16 h16x8 __attribute__((ext_vector_type(8)));
typedef __fp16  fp16x2 __attribute__((ext_vector_type(2)));

union hu8 { unsigned int u[4]; h16x8 v; };

__device__ __forceinline__ unsigned short f2bf_rn(float f) {
  union { float f; unsigned int i; } v; v.f = f;
  unsigned int r = v.i + 0x7FFFu + ((v.i >> 16) & 1u);  // RTNE
  return (unsigned short)(r >> 16);
}
// two f32 -> packed 2x f16 (RTZ) as u32
__device__ __forceinline__ unsigned int pk2(float lo, float hi) {
  fp16x2 h = __builtin_amdgcn_cvt_pkrtz(lo, hi);
  union { fp16x2 h; unsigned int u; } v; v.h = h; return v.u;
}
// AND-mask for one f16 pair from bit kk of two words: lo16 from wlo, hi16 from whi
__device__ __forceinline__ unsigned int bm16(unsigned wlo, unsigned whi, int kk) {
  int mlo, mhi;
  asm("v_bfe_i32 %0, %1, %2, 1" : "=v"(mlo) : "v"(wlo), "v"(kk));  // 0 or ~0
  asm("v_bfe_i32 %0, %1, %2, 1" : "=v"(mhi) : "v"(whi), "v"(kk));
  return ((unsigned)mlo & 0x0000FFFFu) | ((unsigned)mhi & 0xFFFF0000u);
}

// ---- K0: one-time conversions. grid 512x256 ----
__global__ __launch_bounds__(256) void k_prep(
    const float* __restrict__ X, const float* __restrict__ Ww,
    const float* __restrict__ Wcat, const float* __restrict__ proj,
    const float* __restrict__ Wcb, const float* __restrict__ bias,
    const float* __restrict__ prb,
    unsigned short* __restrict__ Xb, unsigned short* __restrict__ WwT,
    unsigned short* __restrict__ WpT, float* __restrict__ bsum)
{
  const int tid = blockIdx.x * 256 + threadIdx.x;  // 0..131071
  {  // X[4096][256] f32 -> bf16 (RTNE), 8 elements/thread
    const float4 a = *(const float4*)(X + (size_t)tid * 8);
    const float4 b = *(const float4*)(X + (size_t)tid * 8 + 4);
    uint4 o;
    o.x = (unsigned)f2bf_rn(a.x) | ((unsigned)f2bf_rn(a.y) << 16);
    o.y = (unsigned)f2bf_rn(a.z) | ((unsigned)f2bf_rn(a.w) << 16);
    o.z = (unsigned)f2bf_rn(b.x) | ((unsigned)f2bf_rn(b.y) << 16);
    o.w = (unsigned)f2bf_rn(b.z) | ((unsigned)f2bf_rn(b.w) << 16);
    *(uint4*)(Xb + (size_t)tid * 8) = o;
  }
  if (tid < 32768) {  // WwT[c][k] = Ww[k][c], bf16
    int c = tid & 127, k = tid >> 7;
    WwT[c * 256 + k] = f2bf_rn(Ww[k * 128 + c]);
  }
  if (tid < 65536) {  // WpT[c][k]: k<256 -> Wcat[k][c], else proj[k-256][c]
    int c = tid & 127, k = tid >> 7;
    float v = (k < 256) ? Wcat[k * 128 + c] : proj[(k - 256) * 128 + c];
    WpT[c * 512 + k] = f2bf_rn(v);
  }
  if (tid < 128) bsum[tid] = Wcb[tid] + bias[tid] + prb[tid];
}

// ---- K0b: coalesced mask -> bit compression. grid 8192 x 512 ----
// One wave per (graph, row, 512-col segment): 32 B/lane float4 reads,
// 8 ballots, lane 0 writes 64 B of packed words [lo0..lo7, hi0..hi7].
__global__ __launch_bounds__(512) void k_bits(
    const float* __restrict__ Dg, const float* __restrict__ Sg,
    unsigned int* __restrict__ bD, unsigned int* __restrict__ bS)
{
  const int wid = blockIdx.x * 8 + (threadIdx.x >> 6);
  const int lane = threadIdx.x & 63;
  const int g = wid >> 15;            // graph
  const int lid = wid & 32767;
  const int row = lid >> 3, cseg = lid & 7;
  const float* src = (g ? Sg : Dg) + (size_t)row * NN + cseg * 512 + lane * 8;
  const float4 a = *(const float4*)(src);
  const float4 b = *(const float4*)(src + 4);
  unsigned long long m[8];
  m[0] = __ballot(a.x != 0.f); m[1] = __ballot(a.y != 0.f);
  m[2] = __ballot(a.z != 0.f); m[3] = __ballot(a.w != 0.f);
  m[4] = __ballot(b.x != 0.f); m[5] = __ballot(b.y != 0.f);
  m[6] = __ballot(b.z != 0.f); m[7] = __ballot(b.w != 0.f);
  if (lane == 0) {
    unsigned int* dst = (g ? bS : bD) + ((size_t)row * 8 + cseg) * 16;
    uint4 w0, w1, w2, w3;
    w0.x = (unsigned)m[0]; w0.y = (unsigned)m[1];
    w0.z = (unsigned)m[2]; w0.w = (unsigned)m[3];
    w1.x = (unsigned)m[4]; w1.y = (unsigned)m[5];
    w1.z = (unsigned)m[6]; w1.w = (unsigned)m[7];
    w2.x = (unsigned)(m[0] >> 32); w2.y = (unsigned)(m[1] >> 32);
    w2.z = (unsigned)(m[2] >> 32); w2.w = (unsigned)(m[3] >> 32);
    w3.x = (unsigned)(m[4] >> 32); w3.y = (unsigned)(m[5] >> 32);
    w3.z = (unsigned)(m[6] >> 32); w3.w = (unsigned)(m[7] >> 32);
    *(uint4*)(dst)      = w0;
    *(uint4*)(dst + 4)  = w1;
    *(uint4*)(dst + 8)  = w2;
    *(uint4*)(dst + 12) = w3;
  }
}

// ---- K1: score GEMM + f2 + f16 exp tables. grid 256 x 512 ----
__global__ __launch_bounds__(512) void k_score(
    const unsigned short* __restrict__ Xb, const unsigned short* __restrict__ WwT,
    const float* __restrict__ Wb, const float* __restrict__ wu,
    const float* __restrict__ wv,
    unsigned short* __restrict__ scT, float* __restrict__ f2,
    unsigned short* __restrict__ E1p, unsigned short* __restrict__ E3p)
{
  const int n0 = blockIdx.x * 16;
  const int h = threadIdx.x >> 6, lane = threadIdx.x & 63;
  const int mr = lane & 15, grp = lane >> 4;
  const unsigned short* ap  = Xb  + (size_t)(n0 + mr) * 256;
  const unsigned short* bpp = WwT + (size_t)(h * 16 + mr) * 256;
  f32x4 acc = {0.f, 0.f, 0.f, 0.f};
  #pragma unroll
  for (int ks = 0; ks < 8; ++ks) {
    bf16x8 a = *(const bf16x8*)(ap  + ks * 32 + grp * 8);
    bf16x8 b = *(const bf16x8*)(bpp + ks * 32 + grp * 8);
    acc = __builtin_amdgcn_mfma_f32_16x16x32_bf16(a, b, acc, 0, 0, 0);
  }
  const float wb = Wb[h * 16 + mr];
  float sc[4];
  #pragma unroll
  for (int r = 0; r < 4; ++r) sc[r] = acc[r] + wb;  // score[n0+grp*4+r][h*16+mr]

  {  // scT[h*16+mr][n0+grp*4 .. +3] f16
    uint2 st;
    st.x = pk2(sc[0], sc[1]);
    st.y = pk2(sc[2], sc[3]);
    *(uint2*)(scT + (size_t)(h * 16 + mr) * NN + n0 + grp * 4) = st;
  }

  const float uw = wu[h * 16 + mr], vw = wv[h * 16 + mr];
  float t1[4], t2[4];
  #pragma unroll
  for (int r = 0; r < 4; ++r) { t1[r] = sc[r] * uw; t2[r] = sc[r] * vw; }
  #pragma unroll
  for (int m = 1; m < 16; m <<= 1) {
    #pragma unroll
    for (int r = 0; r < 4; ++r) {
      t1[r] += __shfl_xor(t1[r], m, 64);
      t2[r] += __shfl_xor(t2[r], m, 64);
    }
  }
  if (mr == 0) {
    *(float4*)(f2 + h * NN + n0 + grp * 4) = make_float4(t2[0], t2[1], t2[2], t2[3]);
    float e1[4], e3[4];
    #pragma unroll
    for (int r = 0; r < 4; ++r) {
      e1[r] = __builtin_amdgcn_exp2f(t1[r] * LOG2E);
      e3[r] = __builtin_amdgcn_exp2f(0.3f * t1[r] * LOG2E);
    }
    uint2 p1, p3;
    p1.x = pk2(e1[0], e1[1]);
    p1.y = pk2(e1[2], e1[3]);
    p3.x = pk2(e3[0], e3[1]);
    p3.y = pk2(e3[2], e3[3]);
    *(uint2*)(E1p + h * NN + n0 + grp * 4) = p1;
    *(uint2*)(E3p + h * NN + n0 + grp * 4) = p3;
  }
}

// ---- K2: dual-graph masked softmax attention, j-split x NS ----
// grid = NS*256 (bx = chunk*256 + tile), 512 thr (8 waves = 8 heads).
// No LDS, no barriers, no scalar loads: per-lane bit words (uint4 vector
// loads, L2-resident 4 MB) + packed-f16 q; mask via v_bfe_i32 AND-mask.
__global__ __launch_bounds__(512, 6) void k_attn(
    const unsigned int* __restrict__ bD, const unsigned int* __restrict__ bS,
    const unsigned short* __restrict__ scT, const unsigned short* __restrict__ E1p,
    const unsigned short* __restrict__ E3p, const float* __restrict__ f2,
    float* __restrict__ pn, float* __restrict__ pd)
{
  const int bx = blockIdx.x;
  const int c = bx >> 8, t = bx & 255;
  const int i0 = t << 4, j0 = c * CHUNK;
  const int h = threadIdx.x >> 6, lane = threadIdx.x & 63;
  const int mr = lane & 15, grp = lane >> 4;

  const float f2v = f2[h * NN + i0 + mr];
  const _Float16 afh = (_Float16)__builtin_amdgcn_exp2f(f2v * LOG2E);
  const _Float16 bfh = (_Float16)__builtin_amdgcn_exp2f(0.3f * f2v * LOG2E);
  const h16x8 af8 = {afh, afh, afh, afh, afh, afh, afh, afh};
  const h16x8 bf8 = {bfh, bfh, bfh, bfh, bfh, bfh, bfh, bfh};
  const _Float16 one = (_Float16)1.f;
  const h16x8 ones = {one, one, one, one, one, one, one, one};

  const _Float16* e1p_ = (const _Float16*)E1p + h * NN + j0 + grp * 8;
  const _Float16* e3p_ = (const _Float16*)E3p + h * NN + j0 + grp * 8;
  const _Float16* scp_ = (const _Float16*)scT + (size_t)(h * 16 + mr) * NN + j0 + grp * 8;
  // bit words for this lane's row, chunk c covers csegs c*2 .. c*2+1
  const unsigned int* bDr = bD + ((size_t)(i0 + mr) * 8 + c * 2) * 16;
  const unsigned int* bSr = bS + ((size_t)(i0 + mr) * 8 + c * 2) * 16;

  f32x4 accD = {0.f,0.f,0.f,0.f}, accS = {0.f,0.f,0.f,0.f};
  f32x4 dnD  = {0.f,0.f,0.f,0.f}, dnS  = {0.f,0.f,0.f,0.f};

  #pragma unroll
  for (int cs = 0; cs < 2; ++cs) {
    #pragma unroll
    for (int h2 = 0; h2 < 2; ++h2) {
      // words [e0..e7] for this (cseg, half): lo-half bits cover itr 0..7
      const unsigned int* wd = bDr + cs * 16 + h2 * 8;
      const unsigned int* ws_ = bSr + cs * 16 + h2 * 8;
      const uint4 d01 = *(const uint4*)(wd);
      const uint4 d23 = *(const uint4*)(wd + 4);
      const uint4 s01 = *(const uint4*)(ws_);
      const uint4 s23 = *(const uint4*)(ws_ + 4);
      #pragma unroll
      for (int itr = 0; itr < 8; ++itr) {
        const int it = cs * 16 + h2 * 8 + itr;
        const h16x8 e1 = *(const h16x8*)(e1p_ + it * 32);
        const h16x8 e3 = *(const h16x8*)(e3p_ + it * 32);
        const h16x8 sv = *(const h16x8*)(scp_ + it * 32);
        const int kk = itr * 4 + grp;

        hu8 Q, AD, AS;
        Q.v = __builtin_elementwise_max(e1 * af8, e3 * bf8);
        AD.u[0] = Q.u[0] & bm16(d01.x, d01.y, kk);
        AD.u[1] = Q.u[1] & bm16(d01.z, d01.w, kk);
        AD.u[2] = Q.u[2] & bm16(d23.x, d23.y, kk);
        AD.u[3] = Q.u[3] & bm16(d23.z, d23.w, kk);
        AS.u[0] = Q.u[0] & bm16(s01.x, s01.y, kk);
        AS.u[1] = Q.u[1] & bm16(s01.z, s01.w, kk);
        AS.u[2] = Q.u[2] & bm16(s23.x, s23.y, kk);
        AS.u[3] = Q.u[3] & bm16(s23.z, s23.w, kk);

        accD = __builtin_amdgcn_mfma_f32_16x16x32_f16(AD.v, sv, accD, 0, 0, 0);
        accS = __builtin_amdgcn_mfma_f32_16x16x32_f16(AS.v, sv, accS, 0, 0, 0);
        dnD  = __builtin_amdgcn_mfma_f32_16x16x32_f16(AD.v, ones, dnD, 0, 0, 0);
        dnS  = __builtin_amdgcn_mfma_f32_16x16x32_f16(AS.v, ones, dnS, 0, 0, 0);
      }
    }
  }

  // partials: pn[((c*256+t)*8+h)*2+g][row][col], pd[((c*256+t)*8+h)*2+g][row]
  float* pnb = pn + ((((size_t)c * 256 + t) * 8 + h) * 2) * 256;
  #pragma unroll
  for (int r = 0; r < 4; ++r) {
    const int row = grp * 4 + r;
    pnb[row * 16 + mr]       = accD[r];
    pnb[256 + row * 16 + mr] = accS[r];
  }
  if (mr == 0) {
    float* pdb = pd + ((((size_t)c * 256 + t) * 8 + h) * 2) * 16;
    #pragma unroll
    for (int r = 0; r < 4; ++r) {
      pdb[grp * 4 + r]      = dnD[r];
      pdb[16 + grp * 4 + r] = dnS[r];
    }
  }
}

// ---- K3: reduce partials, normalize, output GEMM. grid 256 x 512 ----
__global__ __launch_bounds__(512) void k_reduce(
    const float* __restrict__ pn, const float* __restrict__ pd,
    const unsigned short* __restrict__ Xb, const unsigned short* __restrict__ WpT,
    const float* __restrict__ bsum, float* __restrict__ out)
{
  __shared__ unsigned short catT[16][520];  // [row][ S(128) | D(128) | X(256) ]
  const int t = blockIdx.x, i0 = t * 16;
  const int tid = threadIdx.x;
  {  // stage X rows -> catT cols 256..511
    const int r = tid >> 5, x0 = (tid & 31) * 8;
    *(bf16x8*)(&catT[r][256 + x0]) = *(const bf16x8*)(Xb + (size_t)(i0 + r) * 256 + x0);
  }
  const int h = tid >> 6, lane = tid & 63;
  const int mr = lane & 15, grp = lane >> 4;

  #pragma unroll
  for (int r = 0; r < 4; ++r) {
    const int row = grp * 4 + r;
    float vD = 0.f, vS = 0.f, dD = 0.f, dS = 0.f;
    #pragma unroll
    for (int c = 0; c < NS; ++c) {
      const size_t nb = ((((size_t)c * 256 + t) * 8 + h) * 2) * 256;
      const size_t db = ((((size_t)c * 256 + t) * 8 + h) * 2) * 16;
      vD += pn[nb + row * 16 + mr];
      vS += pn[nb + 256 + row * 16 + mr];
      dD += pd[db + row];
      dS += pd[db + 16 + row];
    }
    const float oS = vS * __builtin_amdgcn_rcpf(fmaxf(dS, 1e-30f));
    const float oD = vD * __builtin_amdgcn_rcpf(fmaxf(dD, 1e-30f));
    catT[row][h * 16 + mr]       = f2bf_rn(oS);
    catT[row][128 + h * 16 + mr] = f2bf_rn(oD);
  }
  __syncthreads();

  // phase B: out[16][128] = catT[16][512] @ W'[512][128] + bsum
  f32x4 o = {0.f, 0.f, 0.f, 0.f};
  const unsigned short* wp = WpT + (size_t)(h * 16 + mr) * 512;
  #pragma unroll
  for (int ks = 0; ks < 16; ++ks) {
    bf16x8 a = *(const bf16x8*)(&catT[mr][ks * 32 + grp * 8]);
    bf16x8 b = *(const bf16x8*)(wp + ks * 32 + grp * 8);
    o = __builtin_amdgcn_mfma_f32_16x16x32_bf16(a, b, o, 0, 0, 0);
  }
  const float bs = bsum[h * 16 + mr];
  #pragma unroll
  for (int r = 0; r < 4; ++r)
    out[(size_t)(i0 + grp * 4 + r) * 128 + h * 16 + mr] = o[r] + bs;
}

extern "C" void kernel_launch(void* const* d_in, const int* in_sizes, int n_in,
                              void* d_out, int out_size, void* d_ws, size_t ws_size,
                              hipStream_t stream) {
  const float* X    = (const float*)d_in[0];
  const float* Dg   = (const float*)d_in[1];
  const float* Sg   = (const float*)d_in[2];
  const float* Ww   = (const float*)d_in[3];
  const float* Wb   = (const float*)d_in[4];
  const float* wu   = (const float*)d_in[5];
  const float* wv   = (const float*)d_in[6];
  const float* Wcat = (const float*)d_in[7];
  const float* Wcb  = (const float*)d_in[8];
  const float* bias = (const float*)d_in[9];
  const float* proj = (const float*)d_in[10];
  const float* prb  = (const float*)d_in[11];
  float* out = (float*)d_out;

  char* ws = (char*)d_ws;
  unsigned short* Xb   = (unsigned short*)(ws);              // 2 MB
  unsigned short* scT  = (unsigned short*)(ws + 0x200000);   // 1 MB (f16)
  float*          f2   = (float*)(ws + 0x300000);            // 128 KB
  unsigned short* E1p  = (unsigned short*)(ws + 0x320000);   // 64 KB (f16)
  unsigned short* E3p  = (unsigned short*)(ws + 0x330000);   // 64 KB (f16)
  unsigned short* WwT  = (unsigned short*)(ws + 0x340000);   // 64 KB
  unsigned short* WpT  = (unsigned short*)(ws + 0x350000);   // 128 KB
  float*          bsum = (float*)(ws + 0x370000);            // 512 B
  unsigned int*   bD   = (unsigned int*)(ws + 0x380000);     // 2 MB
  unsigned int*   bS   = (unsigned int*)(ws + 0x580000);     // 2 MB
  float*          pn   = (float*)(ws + 0x780000);            // 16 MB
  float*          pd   = (float*)(ws + 0x1780000);           // 1 MB

  k_prep<<<dim3(512), dim3(256), 0, stream>>>(X, Ww, Wcat, proj, Wcb, bias, prb,
                                              Xb, WwT, WpT, bsum);
  k_bits<<<dim3(8192), dim3(512), 0, stream>>>(Dg, Sg, bD, bS);
  k_score<<<dim3(256), dim3(512), 0, stream>>>(Xb, WwT, Wb, wu, wv, scT, f2, E1p, E3p);
  k_attn<<<dim3(NS * 256), dim3(512), 0, stream>>>(bD, bS, scT, E1p, E3p, f2, pn, pd);
  k_reduce<<<dim3(256), dim3(512), 0, stream>>>(pn, pd, Xb, WpT, bsum, out);
}

// Round 15
// 112.308 us; speedup vs baseline: 1.0042x; 1.0033x over previous
//
#include <hip/hip_runtime.h>
#include <hip/hip_bf16.h>

// GAT MultiHeads, MI355X. N=4096, F_IN=256, H=8, D=16, HD=128.
// All inputs/outputs f32; attention inner loop packed f16 + per-lane bitmasks.
//
// Math identities (vs reference):
//  - logits[h,i,j] = f1[h,j] + f2[h,i]  (rank-1, never materialized)
//  - exp(lrelu(x)) = max(e^x, e^{0.3x})  (exp monotone, lrelu = max(x,0.3x))
//    => q = max(E1[j]*A[i], E3[j]*B[i]); E1=e^f1, E3=e^{0.3f1}, A=e^f2, B=e^{0.3f2}
//  - no max-subtraction: logits bounded (|x| < ~5), softmax ratio invariant
//  - g in {0,1} => mask as bit; applied via v_bfe_i32 sign-mask AND on f16 pairs
//  - denominators = P @ ones via MFMA (idle pipe), lane gets its row sum
//  - fully-masked rows: denom clamp 1e-30 => output row 0 (matches densify)
//
// Pipeline: k_prep (cvt) / k_score (score GEMM + f16 exp tables) /
// k_bits (coalesced ballot compression: 134MB f32 -> 4MB bits, the BW floor) /
// k_attn (j-split x4: no LDS, no barriers, no scalar loads; per-lane bit words)
// / k_reduce (sum partials + output GEMM).
//
// Bit layout: bits[row][cseg][half][e] u32; bit (4*itr+grp) of word (half,e)
//  = mask[row][cseg*512 + half*256 + itr*32 + grp*8 + e]   (itr in [0,8))

#define NN 4096
#define LOG2E 1.44269504088896340736f
#define NS 4          // j-split chunks
#define CHUNK 1024    // NN/NS

typedef short bf16x8 __attribute__((ext_vector_type(8)));
typedef float f32x4  __attribute__((ext_vector_type(4)));
typedef _Float16 h16x8 __attribute__((ext_vector_type(8)));
typedef __fp16  fp16x2 __attribute__((ext_vector_type(2)));

union hu8 { unsigned int u[4]; h16x8 v; };

__device__ __forceinline__ unsigned short f2bf_rn(float f) {
  union { float f; unsigned int i; } v; v.f = f;
  unsigned int r = v.i + 0x7FFFu + ((v.i >> 16) & 1u);  // RTNE
  return (unsigned short)(r >> 16);
}
// two f32 -> packed 2x f16 (RTZ) as u32
__device__ __forceinline__ unsigned int pk2(float lo, float hi) {
  fp16x2 h = __builtin_amdgcn_cvt_pkrtz(lo, hi);
  union { fp16x2 h; unsigned int u; } v; v.h = h; return v.u;
}
// AND-mask for one f16 pair from bit kk of two words: lo16 from wlo, hi16 from whi
__device__ __forceinline__ unsigned int bm16(unsigned wlo, unsigned whi, int kk) {
  int mlo, mhi;
  asm("v_bfe_i32 %0, %1, %2, 1" : "=v"(mlo) : "v"(wlo), "v"(kk));  // 0 or ~0
  asm("v_bfe_i32 %0, %1, %2, 1" : "=v"(mhi) : "v"(whi), "v"(kk));
  return ((unsigned)mlo & 0x0000FFFFu) | ((unsigned)mhi & 0xFFFF0000u);
}

// ---- K0: one-time conversions. grid 512x256 ----
__global__ __launch_bounds__(256) void k_prep(
    const float* __restrict__ X, const float* __restrict__ Ww,
    const float* __restrict__ Wcat, const float* __restrict__ proj,
    const float* __restrict__ Wcb, const float* __restrict__ bias,
    const float* __restrict__ prb,
    unsigned short* __restrict__ Xb, unsigned short* __restrict__ WwT,
    unsigned short* __restrict__ WpT, float* __restrict__ bsum)
{
  const int tid = blockIdx.x * 256 + threadIdx.x;  // 0..131071
  {  // X[4096][256] f32 -> bf16 (RTNE), 8 elements/thread
    const float4 a = *(const float4*)(X + (size_t)tid * 8);
    const float4 b = *(const float4*)(X + (size_t)tid * 8 + 4);
    uint4 o;
    o.x = (unsigned)f2bf_rn(a.x) | ((unsigned)f2bf_rn(a.y) << 16);
    o.y = (unsigned)f2bf_rn(a.z) | ((unsigned)f2bf_rn(a.w) << 16);
    o.z = (unsigned)f2bf_rn(b.x) | ((unsigned)f2bf_rn(b.y) << 16);
    o.w = (unsigned)f2bf_rn(b.z) | ((unsigned)f2bf_rn(b.w) << 16);
    *(uint4*)(Xb + (size_t)tid * 8) = o;
  }
  if (tid < 32768) {  // WwT[c][k] = Ww[k][c], bf16
    int c = tid & 127, k = tid >> 7;
    WwT[c * 256 + k] = f2bf_rn(Ww[k * 128 + c]);
  }
  if (tid < 65536) {  // WpT[c][k]: k<256 -> Wcat[k][c], else proj[k-256][c]
    int c = tid & 127, k = tid >> 7;
    float v = (k < 256) ? Wcat[k * 128 + c] : proj[(k - 256) * 128 + c];
    WpT[c * 512 + k] = f2bf_rn(v);
  }
  if (tid < 128) bsum[tid] = Wcb[tid] + bias[tid] + prb[tid];
}

// ---- K0b: coalesced mask -> bit compression. grid 8192 x 512 ----
// One wave per (graph, row, 512-col segment): 32 B/lane float4 reads,
// 8 ballots, lane 0 writes 64 B of packed words [lo0..lo7, hi0..hi7].
__global__ __launch_bounds__(512) void k_bits(
    const float* __restrict__ Dg, const float* __restrict__ Sg,
    unsigned int* __restrict__ bD, unsigned int* __restrict__ bS)
{
  const int wid = blockIdx.x * 8 + (threadIdx.x >> 6);
  const int lane = threadIdx.x & 63;
  const int g = wid >> 15;            // graph
  const int lid = wid & 32767;
  const int row = lid >> 3, cseg = lid & 7;
  const float* src = (g ? Sg : Dg) + (size_t)row * NN + cseg * 512 + lane * 8;
  const float4 a = *(const float4*)(src);
  const float4 b = *(const float4*)(src + 4);
  unsigned long long m[8];
  m[0] = __ballot(a.x != 0.f); m[1] = __ballot(a.y != 0.f);
  m[2] = __ballot(a.z != 0.f); m[3] = __ballot(a.w != 0.f);
  m[4] = __ballot(b.x != 0.f); m[5] = __ballot(b.y != 0.f);
  m[6] = __ballot(b.z != 0.f); m[7] = __ballot(b.w != 0.f);
  if (lane == 0) {
    unsigned int* dst = (g ? bS : bD) + ((size_t)row * 8 + cseg) * 16;
    uint4 w0, w1, w2, w3;
    w0.x = (unsigned)m[0]; w0.y = (unsigned)m[1];
    w0.z = (unsigned)m[2]; w0.w = (unsigned)m[3];
    w1.x = (unsigned)m[4]; w1.y = (unsigned)m[5];
    w1.z = (unsigned)m[6]; w1.w = (unsigned)m[7];
    w2.x = (unsigned)(m[0] >> 32); w2.y = (unsigned)(m[1] >> 32);
    w2.z = (unsigned)(m[2] >> 32); w2.w = (unsigned)(m[3] >> 32);
    w3.x = (unsigned)(m[4] >> 32); w3.y = (unsigned)(m[5] >> 32);
    w3.z = (unsigned)(m[6] >> 32); w3.w = (unsigned)(m[7] >> 32);
    *(uint4*)(dst)      = w0;
    *(uint4*)(dst + 4)  = w1;
    *(uint4*)(dst + 8)  = w2;
    *(uint4*)(dst + 12) = w3;
  }
}

// ---- K1: score GEMM + f2 + f16 exp tables. grid 256 x 512 ----
__global__ __launch_bounds__(512) void k_score(
    const unsigned short* __restrict__ Xb, const unsigned short* __restrict__ WwT,
    const float* __restrict__ Wb, const float* __restrict__ wu,
    const float* __restrict__ wv,
    unsigned short* __restrict__ scT, float* __restrict__ f2,
    unsigned short* __restrict__ E1p, unsigned short* __restrict__ E3p)
{
  const int n0 = blockIdx.x * 16;
  const int h = threadIdx.x >> 6, lane = threadIdx.x & 63;
  const int mr = lane & 15, grp = lane >> 4;
  const unsigned short* ap  = Xb  + (size_t)(n0 + mr) * 256;
  const unsigned short* bpp = WwT + (size_t)(h * 16 + mr) * 256;
  f32x4 acc = {0.f, 0.f, 0.f, 0.f};
  #pragma unroll
  for (int ks = 0; ks < 8; ++ks) {
    bf16x8 a = *(const bf16x8*)(ap  + ks * 32 + grp * 8);
    bf16x8 b = *(const bf16x8*)(bpp + ks * 32 + grp * 8);
    acc = __builtin_amdgcn_mfma_f32_16x16x32_bf16(a, b, acc, 0, 0, 0);
  }
  const float wb = Wb[h * 16 + mr];
  float sc[4];
  #pragma unroll
  for (int r = 0; r < 4; ++r) sc[r] = acc[r] + wb;  // score[n0+grp*4+r][h*16+mr]

  {  // scT[h*16+mr][n0+grp*4 .. +3] f16
    uint2 st;
    st.x = pk2(sc[0], sc[1]);
    st.y = pk2(sc[2], sc[3]);
    *(uint2*)(scT + (size_t)(h * 16 + mr) * NN + n0 + grp * 4) = st;
  }

  const float uw = wu[h * 16 + mr], vw = wv[h * 16 + mr];
  float t1[4], t2[4];
  #pragma unroll
  for (int r = 0; r < 4; ++r) { t1[r] = sc[r] * uw; t2[r] = sc[r] * vw; }
  #pragma unroll
  for (int m = 1; m < 16; m <<= 1) {
    #pragma unroll
    for (int r = 0; r < 4; ++r) {
      t1[r] += __shfl_xor(t1[r], m, 64);
      t2[r] += __shfl_xor(t2[r], m, 64);
    }
  }
  if (mr == 0) {
    *(float4*)(f2 + h * NN + n0 + grp * 4) = make_float4(t2[0], t2[1], t2[2], t2[3]);
    float e1[4], e3[4];
    #pragma unroll
    for (int r = 0; r < 4; ++r) {
      e1[r] = __builtin_amdgcn_exp2f(t1[r] * LOG2E);
      e3[r] = __builtin_amdgcn_exp2f(0.3f * t1[r] * LOG2E);
    }
    uint2 p1, p3;
    p1.x = pk2(e1[0], e1[1]);
    p1.y = pk2(e1[2], e1[3]);
    p3.x = pk2(e3[0], e3[1]);
    p3.y = pk2(e3[2], e3[3]);
    *(uint2*)(E1p + h * NN + n0 + grp * 4) = p1;
    *(uint2*)(E3p + h * NN + n0 + grp * 4) = p3;
  }
}

// ---- K2: dual-graph masked softmax attention, j-split x NS ----
// grid = NS*256 (bx = chunk*256 + tile), 512 thr (8 waves = 8 heads).
// No LDS, no barriers, no scalar loads: per-lane bit words (uint4 vector
// loads, L2-resident 4 MB) + packed-f16 q; mask via v_bfe_i32 AND-mask.
__global__ __launch_bounds__(512, 6) void k_attn(
    const unsigned int* __restrict__ bD, const unsigned int* __restrict__ bS,
    const unsigned short* __restrict__ scT, const unsigned short* __restrict__ E1p,
    const unsigned short* __restrict__ E3p, const float* __restrict__ f2,
    float* __restrict__ pn, float* __restrict__ pd)
{
  const int bx = blockIdx.x;
  const int c = bx >> 8, t = bx & 255;
  const int i0 = t << 4, j0 = c * CHUNK;
  const int h = threadIdx.x >> 6, lane = threadIdx.x & 63;
  const int mr = lane & 15, grp = lane >> 4;

  const float f2v = f2[h * NN + i0 + mr];
  const _Float16 afh = (_Float16)__builtin_amdgcn_exp2f(f2v * LOG2E);
  const _Float16 bfh = (_Float16)__builtin_amdgcn_exp2f(0.3f * f2v * LOG2E);
  const h16x8 af8 = {afh, afh, afh, afh, afh, afh, afh, afh};
  const h16x8 bf8 = {bfh, bfh, bfh, bfh, bfh, bfh, bfh, bfh};
  const _Float16 one = (_Float16)1.f;
  const h16x8 ones = {one, one, one, one, one, one, one, one};

  const _Float16* e1p_ = (const _Float16*)E1p + h * NN + j0 + grp * 8;
  const _Float16* e3p_ = (const _Float16*)E3p + h * NN + j0 + grp * 8;
  const _Float16* scp_ = (const _Float16*)scT + (size_t)(h * 16 + mr) * NN + j0 + grp * 8;
  // bit words for this lane's row, chunk c covers csegs c*2 .. c*2+1
  const unsigned int* bDr = bD + ((size_t)(i0 + mr) * 8 + c * 2) * 16;
  const unsigned int* bSr = bS + ((size_t)(i0 + mr) * 8 + c * 2) * 16;

  f32x4 accD = {0.f,0.f,0.f,0.f}, accS = {0.f,0.f,0.f,0.f};
  f32x4 dnD  = {0.f,0.f,0.f,0.f}, dnS  = {0.f,0.f,0.f,0.f};

  #pragma unroll
  for (int cs = 0; cs < 2; ++cs) {
    #pragma unroll
    for (int h2 = 0; h2 < 2; ++h2) {
      // words [e0..e7] for this (cseg, half): lo-half bits cover itr 0..7
      const unsigned int* wd = bDr + cs * 16 + h2 * 8;
      const unsigned int* ws_ = bSr + cs * 16 + h2 * 8;
      const uint4 d01 = *(const uint4*)(wd);
      const uint4 d23 = *(const uint4*)(wd + 4);
      const uint4 s01 = *(const uint4*)(ws_);
      const uint4 s23 = *(const uint4*)(ws_ + 4);
      #pragma unroll
      for (int itr = 0; itr < 8; ++itr) {
        const int it = cs * 16 + h2 * 8 + itr;
        const h16x8 e1 = *(const h16x8*)(e1p_ + it * 32);
        const h16x8 e3 = *(const h16x8*)(e3p_ + it * 32);
        const h16x8 sv = *(const h16x8*)(scp_ + it * 32);
        const int kk = itr * 4 + grp;

        hu8 Q, AD, AS;
        Q.v = __builtin_elementwise_max(e1 * af8, e3 * bf8);
        AD.u[0] = Q.u[0] & bm16(d01.x, d01.y, kk);
        AD.u[1] = Q.u[1] & bm16(d01.z, d01.w, kk);
        AD.u[2] = Q.u[2] & bm16(d23.x, d23.y, kk);
        AD.u[3] = Q.u[3] & bm16(d23.z, d23.w, kk);
        AS.u[0] = Q.u[0] & bm16(s01.x, s01.y, kk);
        AS.u[1] = Q.u[1] & bm16(s01.z, s01.w, kk);
        AS.u[2] = Q.u[2] & bm16(s23.x, s23.y, kk);
        AS.u[3] = Q.u[3] & bm16(s23.z, s23.w, kk);

        accD = __builtin_amdgcn_mfma_f32_16x16x32_f16(AD.v, sv, accD, 0, 0, 0);
        accS = __builtin_amdgcn_mfma_f32_16x16x32_f16(AS.v, sv, accS, 0, 0, 0);
        dnD  = __builtin_amdgcn_mfma_f32_16x16x32_f16(AD.v, ones, dnD, 0, 0, 0);
        dnS  = __builtin_amdgcn_mfma_f32_16x16x32_f16(AS.v, ones, dnS, 0, 0, 0);
      }
    }
  }

  // partials: pn[((c*256+t)*8+h)*2+g][row][col], pd[((c*256+t)*8+h)*2+g][row]
  float* pnb = pn + ((((size_t)c * 256 + t) * 8 + h) * 2) * 256;
  #pragma unroll
  for (int r = 0; r < 4; ++r) {
    const int row = grp * 4 + r;
    pnb[row * 16 + mr]       = accD[r];
    pnb[256 + row * 16 + mr] = accS[r];
  }
  if (mr == 0) {
    float* pdb = pd + ((((size_t)c * 256 + t) * 8 + h) * 2) * 16;
    #pragma unroll
    for (int r = 0; r < 4; ++r) {
      pdb[grp * 4 + r]      = dnD[r];
      pdb[16 + grp * 4 + r] = dnS[r];
    }
  }
}

// ---- K3: reduce partials, normalize, output GEMM. grid 256 x 512 ----
__global__ __launch_bounds__(512) void k_reduce(
    const float* __restrict__ pn, const float* __restrict__ pd,
    const unsigned short* __restrict__ Xb, const unsigned short* __restrict__ WpT,
    const float* __restrict__ bsum, float* __restrict__ out)
{
  __shared__ unsigned short catT[16][520];  // [row][ S(128) | D(128) | X(256) ]
  const int t = blockIdx.x, i0 = t * 16;
  const int tid = threadIdx.x;
  {  // stage X rows -> catT cols 256..511
    const int r = tid >> 5, x0 = (tid & 31) * 8;
    *(bf16x8*)(&catT[r][256 + x0]) = *(const bf16x8*)(Xb + (size_t)(i0 + r) * 256 + x0);
  }
  const int h = tid >> 6, lane = tid & 63;
  const int mr = lane & 15, grp = lane >> 4;

  #pragma unroll
  for (int r = 0; r < 4; ++r) {
    const int row = grp * 4 + r;
    float vD = 0.f, vS = 0.f, dD = 0.f, dS = 0.f;
    #pragma unroll
    for (int c = 0; c < NS; ++c) {
      const size_t nb = ((((size_t)c * 256 + t) * 8 + h) * 2) * 256;
      const size_t db = ((((size_t)c * 256 + t) * 8 + h) * 2) * 16;
      vD += pn[nb + row * 16 + mr];
      vS += pn[nb + 256 + row * 16 + mr];
      dD += pd[db + row];
      dS += pd[db + 16 + row];
    }
    const float oS = vS * __builtin_amdgcn_rcpf(fmaxf(dS, 1e-30f));
    const float oD = vD * __builtin_amdgcn_rcpf(fmaxf(dD, 1e-30f));
    catT[row][h * 16 + mr]       = f2bf_rn(oS);
    catT[row][128 + h * 16 + mr] = f2bf_rn(oD);
  }
  __syncthreads();

  // phase B: out[16][128] = catT[16][512] @ W'[512][128] + bsum
  f32x4 o = {0.f, 0.f, 0.f, 0.f};
  const unsigned short* wp = WpT + (size_t)(h * 16 + mr) * 512;
  #pragma unroll
  for (int ks = 0; ks < 16; ++ks) {
    bf16x8 a = *(const bf16x8*)(&catT[mr][ks * 32 + grp * 8]);
    bf16x8 b = *(const bf16x8*)(wp + ks * 32 + grp * 8);
    o = __builtin_amdgcn_mfma_f32_16x16x32_bf16(a, b, o, 0, 0, 0);
  }
  const float bs = bsum[h * 16 + mr];
  #pragma unroll
  for (int r = 0; r < 4; ++r)
    out[(size_t)(i0 + grp * 4 + r) * 128 + h * 16 + mr] = o[r] + bs;
}

extern "C" void kernel_launch(void* const* d_in, const int* in_sizes, int n_in,
                              void* d_out, int out_size, void* d_ws, size_t ws_size,
                              hipStream_t stream) {
  const float* X    = (const float*)d_in[0];
  const float* Dg   = (const float*)d_in[1];
  const float* Sg   = (const float*)d_in[2];
  const float* Ww   = (const float*)d_in[3];
  const float* Wb   = (const float*)d_in[4];
  const float* wu   = (const float*)d_in[5];
  const float* wv   = (const float*)d_in[6];
  const float* Wcat = (const float*)d_in[7];
  const float* Wcb  = (const float*)d_in[8];
  const float* bias = (const float*)d_in[9];
  const float* proj = (const float*)d_in[10];
  const float* prb  = (const float*)d_in[11];
  float* out = (float*)d_out;

  char* ws = (char*)d_ws;
  unsigned short* Xb   = (unsigned short*)(ws);              // 2 MB
  unsigned short* scT  = (unsigned short*)(ws + 0x200000);   // 1 MB (f16)
  float*          f2   = (float*)(ws + 0x300000);            // 128 KB
  unsigned short* E1p  = (unsigned short*)(ws + 0x320000);   // 64 KB (f16)
  unsigned short* E3p  = (unsigned short*)(ws + 0x330000);   // 64 KB (f16)
  unsigned short* WwT  = (unsigned short*)(ws + 0x340000);   // 64 KB
  unsigned short* WpT  = (unsigned short*)(ws + 0x350000);   // 128 KB
  float*          bsum = (float*)(ws + 0x370000);            // 512 B
  unsigned int*   bD   = (unsigned int*)(ws + 0x380000);     // 2 MB
  unsigned int*   bS   = (unsigned int*)(ws + 0x580000);     // 2 MB
  float*          pn   = (float*)(ws + 0x780000);            // 16 MB
  float*          pd   = (float*)(ws + 0x1780000);           // 1 MB

  k_prep<<<dim3(512), dim3(256), 0, stream>>>(X, Ww, Wcat, proj, Wcb, bias, prb,
                                              Xb, WwT, WpT, bsum);
  k_bits<<<dim3(8192), dim3(512), 0, stream>>>(Dg, Sg, bD, bS);
  k_score<<<dim3(256), dim3(512), 0, stream>>>(Xb, WwT, Wb, wu, wv, scT, f2, E1p, E3p);
  k_attn<<<dim3(NS * 256), dim3(512), 0, stream>>>(bD, bS, scT, E1p, E3p, f2, pn, pd);
  k_reduce<<<dim3(256), dim3(512), 0, stream>>>(pn, pd, Xb, WpT, bsum, out);
}